// Round 12
// baseline (208.597 us; speedup 1.0000x reference)
//
#include <hip/hip_runtime.h>
#include <hip/hip_bf16.h>
#include <cstdint>
#include <cstddef>

typedef __bf16 bf16;
typedef bf16 bf16x8 __attribute__((ext_vector_type(8)));
typedef bf16 bf16x4 __attribute__((ext_vector_type(4)));
typedef float floatx4 __attribute__((ext_vector_type(4)));
typedef int intx8 __attribute__((ext_vector_type(8)));

#define DEVI __device__ __forceinline__

#define C_  512
#define HW_ 4096
#define B_  2
#define M_  8192   // B_*HW_
#define TK  64

// NOTE (R11 lesson): moving l to a pv ones-column + normalizing in proj +
// removing the memset passed the first call but FAILED the post-timing replay
// check. This file keeps the R10 dataflow: l zeroed by memset, accumulated by
// atomics in qk, consumed in pv. Every ws byte read is written every call.

DEVI floatx4 mfma16(bf16x8 a, bf16x8 b, floatx4 c) {
  return __builtin_amdgcn_mfma_f32_16x16x32_bf16(a, b, c, 0, 0, 0);
}

// fp8 e4m3 MX-scaled MFMA with unit scales (E8M0 127 = 2^0): plain fp8 GEMM
// at 2x bf16 rate, K=128 per instruction. cbsz=0/blgp=0 -> fp8 A/B.
DEVI floatx4 mfma_fp8(intx8 a, intx8 b, floatx4 c) {
  return __builtin_amdgcn_mfma_scale_f32_16x16x128_f8f6f4(a, b, c, 0, 0,
                                                          0, 127, 0, 127);
}

// Direct HBM->LDS DMA, 16B per lane. LDS dest is wave-uniform base + lane*16.
DEVI void gload16(const void* g, void* lds) {
  using gp = const __attribute__((address_space(1))) unsigned int*;
  using lp = __attribute__((address_space(3))) unsigned int*;
  __builtin_amdgcn_global_load_lds(
      reinterpret_cast<gp>(reinterpret_cast<uintptr_t>(g)),
      reinterpret_cast<lp>((unsigned int)(uintptr_t)lds), 16, 0, 0);
}

// float -> fp8 e4m3 byte (OCP on gfx950)
DEVI uint32_t f32_to_fp8(float x) {
  return (uint32_t)__builtin_amdgcn_cvt_pk_fp8_f32(x, x, 0, false) & 0xffu;
}
DEVI int pack4_fp8(float a, float b, float c, float d) {
  int pk = __builtin_amdgcn_cvt_pk_fp8_f32(a, b, 0, false);
  return __builtin_amdgcn_cvt_pk_fp8_f32(c, d, pk, true);
}

// ---------------- GroupNorm partial sums: coalesced float4, 512 blocks ------
__global__ __launch_bounds__(256) void gn_part(const float* __restrict__ x,
                                               float* __restrict__ pp) {
  int blk = blockIdx.x;              // 0..511
  int batch = blk >> 8;
  int pix0 = (blk & 255) * 16;
  int t = threadIdx.x;
  int c4 = (t & 127) << 2;           // channel quad (one group)
  int ph = t >> 7;                   // 0/1 pixel phase
  const float* px = x + (size_t)batch * HW_ * C_ + (size_t)(pix0 + ph) * C_ + c4;
  float s1 = 0.f, s2 = 0.f;
#pragma unroll
  for (int i = 0; i < 8; i++) {
    float4 v = *reinterpret_cast<const float4*>(px + (size_t)i * 2 * C_);
    s1 += v.x + v.y + v.z + v.w;
    s2 += v.x * v.x + v.y * v.y + v.z * v.z + v.w * v.w;
  }
  __shared__ float l1[256], l2[256];
  l1[t] = s1; l2[t] = s2;
  __syncthreads();
  if (t < 32) {                      // group g = t: slots g*4+j (+128)
    float a = 0.f, b2 = 0.f;
#pragma unroll
    for (int j = 0; j < 4; j++) {
      a  += l1[t * 4 + j] + l1[t * 4 + j + 128];
      b2 += l2[t * 4 + j] + l2[t * 4 + j + 128];
    }
    pp[blk * 32 + t] = a;
    pp[512 * 32 + blk * 32 + t] = b2;
  }
}

// ---------------- GroupNorm finish: reduce 256 partials per (b,g) -----------
__global__ __launch_bounds__(256) void gn_finish(const float* __restrict__ pp,
                                                 float* __restrict__ stats) {
  int bg = blockIdx.x;               // b*32+g
  int b = bg >> 5, g = bg & 31;
  int t = threadIdx.x;               // one partial-block per thread
  float s1 = pp[(b * 256 + t) * 32 + g];
  float s2 = pp[512 * 32 + (b * 256 + t) * 32 + g];
  for (int off = 32; off; off >>= 1) {
    s1 += __shfl_down(s1, off);
    s2 += __shfl_down(s2, off);
  }
  __shared__ float r1[4], r2[4];
  int wid = t >> 6;
  if ((t & 63) == 0) { r1[wid] = s1; r2[wid] = s2; }
  __syncthreads();
  if (t == 0) {
    s1 = r1[0] + r1[1] + r1[2] + r1[3];
    s2 = r2[0] + r2[1] + r2[2] + r2[3];
    float inv = 1.0f / (HW_ * 16);
    float mean = s1 * inv;
    float var  = s2 * inv - mean * mean;
    stats[bg]      = mean;
    stats[64 + bg] = rsqrtf(var + 1e-5f);
  }
}

// ---------------- Apply GN -> h8 fp8 (M_ x C_) ------------------------------
__global__ __launch_bounds__(256) void gn_apply(const float* __restrict__ x,
                                                const float* __restrict__ gamma,
                                                const float* __restrict__ beta,
                                                const float* __restrict__ stats,
                                                uint8_t* __restrict__ h8) {
  int idx = blockIdx.x * 256 + threadIdx.x;    // 4 elems each
  int m  = idx >> 7;
  int c4 = (idx & 127) << 2;
  int b = m >> 12;
  int g = c4 >> 4;
  float mean = stats[(b << 5) + g];
  float rs   = stats[64 + (b << 5) + g];
  const float4 xv = *reinterpret_cast<const float4*>(x + (size_t)m * C_ + c4);
  const float4 gv = *reinterpret_cast<const float4*>(gamma + c4);
  const float4 bv = *reinterpret_cast<const float4*>(beta + c4);
  int pk = pack4_fp8((xv.x - mean) * rs * gv.x + bv.x,
                     (xv.y - mean) * rs * gv.y + bv.y,
                     (xv.z - mean) * rs * gv.z + bv.z,
                     (xv.w - mean) * rs * gv.w + bv.w);
  *reinterpret_cast<int*>(h8 + (size_t)m * C_ + c4) = pk;
}

// ---- Transpose weights: w8[z][n][k] = fp8(w_z[k][n]) z<3; wtp bf16 for wp --
__global__ __launch_bounds__(256) void wtrans(const float* __restrict__ wq,
                                              const float* __restrict__ wk,
                                              const float* __restrict__ wv,
                                              const float* __restrict__ wp,
                                              uint8_t* __restrict__ w8,
                                              bf16* __restrict__ wtp) {
  int z = blockIdx.z;
  const float* w = (z == 0) ? wq : (z == 1) ? wk : (z == 2) ? wv : wp;
  __shared__ float t[32][33];
  int k0 = blockIdx.x * 32, n0 = blockIdx.y * 32;
  int r = threadIdx.x >> 5, cc = threadIdx.x & 31;
  for (int i = 0; i < 4; i++) {
    int rr = r + i * 8;
    t[rr][cc] = w[(size_t)(k0 + rr) * C_ + n0 + cc];
  }
  __syncthreads();
  if (z < 3) {
    uint8_t* dst = w8 + (size_t)z * C_ * C_;
    for (int i = 0; i < 4; i++) {
      int rr = r + i * 8;
      dst[(size_t)(n0 + rr) * C_ + k0 + cc] = (uint8_t)f32_to_fp8(t[cc][rr]);
    }
  } else {
    for (int i = 0; i < 4; i++) {
      int rr = r + i * 8;
      wtp[(size_t)(n0 + rr) * C_ + k0 + cc] = (bf16)t[cc][rr];
    }
  }
}

// ---- m97-style bf16 GEMM mainloop, templated tile: C(BM x BN) = A * Bt^T ---
// A-frag: A[m=lane&15][k=quad*8+j]; C/D: col=lane&15, row=quad*4+reg.
template <int BM, int BN, int MT, int NT>
DEVI void gemm_main(const bf16* __restrict__ A, int lda,
                    const bf16* __restrict__ Bt, int ldb,
                    int K, floatx4 (&acc)[MT][NT]) {
  constexpr int WCOLS = BN / (NT * 16);
  __shared__ __align__(16) bf16 As[BM * TK];
  __shared__ __align__(16) bf16 Bs[BN * TK];
  int tid = threadIdx.x;
  int w = tid >> 6, lane = tid & 63;
  int wrow = w / WCOLS, wcol = w % WCOLS;
  int col = lane & 15, quad = lane >> 4;
#pragma unroll
  for (int mt = 0; mt < MT; mt++)
#pragma unroll
    for (int nt = 0; nt < NT; nt++)
      acc[mt][nt] = floatx4{0.f, 0.f, 0.f, 0.f};
  for (int k0 = 0; k0 < K; k0 += TK) {
    __syncthreads();
#pragma unroll
    for (int i = 0; i < BM / 32; i++) {
      int id = tid + i * 256;                // row=id>>3, c8=id&7
      gload16(A + (size_t)(id >> 3) * lda + k0 + (id & 7) * 8, As + id * 8);
    }
#pragma unroll
    for (int i = 0; i < BN / 32; i++) {
      int id = tid + i * 256;
      gload16(Bt + (size_t)(id >> 3) * ldb + k0 + (id & 7) * 8, Bs + id * 8);
    }
    __syncthreads();                         // drains vmcnt -> LDS valid
#pragma unroll
    for (int kk = 0; kk < 2; kk++) {
      bf16x8 af[MT], bf[NT];
#pragma unroll
      for (int mt = 0; mt < MT; mt++)
        af[mt] = *reinterpret_cast<const bf16x8*>(
            As + (wrow * MT * 16 + mt * 16 + col) * TK + kk * 32 + quad * 8);
#pragma unroll
      for (int nt = 0; nt < NT; nt++)
        bf[nt] = *reinterpret_cast<const bf16x8*>(
            Bs + (wcol * NT * 16 + nt * 16 + col) * TK + kk * 32 + quad * 8);
#pragma unroll
      for (int mt = 0; mt < MT; mt++)
#pragma unroll
        for (int nt = 0; nt < NT; nt++)
          acc[mt][nt] = mfma16(af[mt], bf[nt], acc[mt][nt]);
    }
  }
}

// ---- fp8 MX GEMM mainloop: TK=128 bytes/row; A-frag 32B/lane (k=quad*32+j) -
template <int BM, int BN, int MT, int NT>
DEVI void gemm_fp8(const uint8_t* __restrict__ A, int lda,
                   const uint8_t* __restrict__ Bt, int ldb,
                   int K, floatx4 (&acc)[MT][NT]) {
  constexpr int WCOLS = BN / (NT * 16);
  __shared__ __align__(16) uint8_t As[BM * 128];
  __shared__ __align__(16) uint8_t Bs[BN * 128];
  int tid = threadIdx.x;
  int w = tid >> 6, lane = tid & 63;
  int wrow = w / WCOLS, wcol = w % WCOLS;
  int col = lane & 15, quad = lane >> 4;
#pragma unroll
  for (int mt = 0; mt < MT; mt++)
#pragma unroll
    for (int nt = 0; nt < NT; nt++)
      acc[mt][nt] = floatx4{0.f, 0.f, 0.f, 0.f};
  for (int k0 = 0; k0 < K; k0 += 128) {
    __syncthreads();
#pragma unroll
    for (int i = 0; i < BM / 32; i++) {      // row = id>>3 (8 lanes x 16B = 128B)
      int id = tid + i * 256;
      gload16(A + (size_t)(id >> 3) * lda + k0 + (id & 7) * 16, As + id * 16);
    }
#pragma unroll
    for (int i = 0; i < BN / 32; i++) {
      int id = tid + i * 256;
      gload16(Bt + (size_t)(id >> 3) * ldb + k0 + (id & 7) * 16, Bs + id * 16);
    }
    __syncthreads();                         // drains vmcnt -> LDS valid
    intx8 af[MT], bf[NT];
#pragma unroll
    for (int mt = 0; mt < MT; mt++)
      af[mt] = *reinterpret_cast<const intx8*>(
          As + (wrow * MT * 16 + mt * 16 + col) * 128 + quad * 32);
#pragma unroll
    for (int nt = 0; nt < NT; nt++)
      bf[nt] = *reinterpret_cast<const intx8*>(
          Bs + (wcol * NT * 16 + nt * 16 + col) * 128 + quad * 32);
#pragma unroll
    for (int mt = 0; mt < MT; mt++)
#pragma unroll
      for (int nt = 0; nt < NT; nt++)
        acc[mt][nt] = mfma_fp8(af[mt], bf[nt], acc[mt][nt]);
  }
}

// ---------------- QKV fp8 GEMM (h8 x w8): q8, k8, vt8 -----------------------
// 128x64 tile -> grid (64, 8, 3) = 1536 blocks (6/CU). K=512 -> 4 iters.
__global__ __launch_bounds__(256) void gemm_qkv(const uint8_t* __restrict__ h8,
                                                const uint8_t* __restrict__ w8,
                                                const float* __restrict__ bq,
                                                const float* __restrict__ bk,
                                                const float* __restrict__ bv,
                                                uint8_t* __restrict__ q8,
                                                uint8_t* __restrict__ k8,
                                                uint8_t* __restrict__ vt8) {
  int z = blockIdx.z;
  int m0 = blockIdx.x * 128, n0 = blockIdx.y * 64;
  floatx4 acc[2][4];
  gemm_fp8<128, 64, 2, 4>(h8 + (size_t)m0 * C_, C_,
                          w8 + (size_t)z * C_ * C_ + (size_t)n0 * C_, C_, C_, acc);
  int tid = threadIdx.x, w = tid >> 6, lane = tid & 63;
  int col = lane & 15, quad = lane >> 4;
  const float* bias = (z == 0) ? bq : (z == 1) ? bk : bv;
  if (z < 2) {
    uint8_t* out = (z == 0) ? q8 : k8;
#pragma unroll
    for (int mt = 0; mt < 2; mt++)
#pragma unroll
      for (int nt = 0; nt < 4; nt++) {
        int n = n0 + nt * 16 + col;
        float bb = bias[n];
#pragma unroll
        for (int r = 0; r < 4; r++) {
          int m = m0 + w * 32 + mt * 16 + quad * 4 + r;
          out[(size_t)m * C_ + n] = (uint8_t)f32_to_fp8(acc[mt][nt][r] + bb);
        }
      }
  } else {
    // vt8[b][c][s] = fp8(v[b*4096+s][c]); 4 consecutive s -> packed int store
#pragma unroll
    for (int mt = 0; mt < 2; mt++)
#pragma unroll
      for (int nt = 0; nt < 4; nt++) {
        int n = n0 + nt * 16 + col;
        float bb = bias[n];
        int mbase = m0 + w * 32 + mt * 16 + quad * 4;
        int b = mbase >> 12;
        int s = mbase & 4095;
        int pk = pack4_fp8(acc[mt][nt][0] + bb, acc[mt][nt][1] + bb,
                           acc[mt][nt][2] + bb, acc[mt][nt][3] + bb);
        *reinterpret_cast<int*>(vt8 + ((size_t)b * C_ + n) * HW_ + s) = pk;
      }
  }
}

// ---------------- QK^T fp8 GEMM -> P8 = fp8(exp(S*scale)), l += rowsum ------
// 128x64 tile -> grid (32, 64, B) = 4096 blocks (16/CU). K=512 -> 4 iters.
// l sums the PRE-ROUNDING float p (saves 32 decodes; mean-zero fp8 rounding
// mismatch vs PV ~0.1% relative -> negligible).
__global__ __launch_bounds__(256) void gemm_qk(const uint8_t* __restrict__ q8,
                                               const uint8_t* __restrict__ k8,
                                               uint8_t* __restrict__ P8,
                                               float* __restrict__ l) {
  int b = blockIdx.z;
  int m0 = blockIdx.x * 128, n0 = blockIdx.y * 64;
  floatx4 acc[2][4];
  gemm_fp8<128, 64, 2, 4>(q8 + ((size_t)b * HW_ + m0) * C_, C_,
                          k8 + ((size_t)b * HW_ + n0) * C_, C_, C_, acc);
  int tid = threadIdx.x, w = tid >> 6, lane = tid & 63;
  int col = lane & 15, quad = lane >> 4;
  const float sl2e = 0.044194173824159216f * 1.4426950408889634f; // scale*log2e
  uint8_t* Pb = P8 + (size_t)b * HW_ * HW_;
  float* lb = l + (size_t)b * HW_;
#pragma unroll
  for (int mt = 0; mt < 2; mt++) {
    float rs[4] = {0.f, 0.f, 0.f, 0.f};
#pragma unroll
    for (int nt = 0; nt < 4; nt++) {
      int n = n0 + nt * 16 + col;
      float p0 = exp2f(acc[mt][nt][0] * sl2e);
      float p1 = exp2f(acc[mt][nt][1] * sl2e);
      float p2 = exp2f(acc[mt][nt][2] * sl2e);
      float p3 = exp2f(acc[mt][nt][3] * sl2e);
      int pk = pack4_fp8(p0, p1, p2, p3);
      size_t base = (size_t)(m0 + w * 32 + mt * 16 + quad * 4) * HW_ + n;
      Pb[base]           = (uint8_t)pk;
      Pb[base + HW_]     = (uint8_t)((unsigned)pk >> 8);
      Pb[base + 2 * HW_] = (uint8_t)((unsigned)pk >> 16);
      Pb[base + 3 * HW_] = (uint8_t)((unsigned)pk >> 24);
      rs[0] += p0; rs[1] += p1; rs[2] += p2; rs[3] += p3;
    }
    // reduce over the 16 col-lanes (xor keeps quad fixed)
#pragma unroll
    for (int off = 1; off < 16; off <<= 1)
#pragma unroll
      for (int r = 0; r < 4; r++)
        rs[r] += __shfl_xor(rs[r], off);
    if (col == 0)
#pragma unroll
      for (int r = 0; r < 4; r++)
        atomicAdd(&lb[m0 + w * 32 + mt * 16 + quad * 4 + r], rs[r]);
  }
}

// ---------------- PV fp8 GEMM: O = P8 * V8^T, normalize by l -> o bf16 ------
// 64x64 tile -> grid (64, 8, B) = 1024 blocks (4/CU). K=4096 -> 32 iters.
__global__ __launch_bounds__(256) void gemm_pv(const uint8_t* __restrict__ P8,
                                               const uint8_t* __restrict__ vt8,
                                               const float* __restrict__ l,
                                               bf16* __restrict__ o) {
  int b = blockIdx.z;
  int m0 = blockIdx.x * 64, n0 = blockIdx.y * 64;
  floatx4 acc[1][4];
  gemm_fp8<64, 64, 1, 4>(P8 + (size_t)b * HW_ * HW_ + (size_t)m0 * HW_, HW_,
                         vt8 + ((size_t)b * C_ + n0) * HW_, HW_, HW_, acc);
  int tid = threadIdx.x, w = tid >> 6, lane = tid & 63;
  int col = lane & 15, quad = lane >> 4;
  const float* lb = l + (size_t)b * HW_;
  bf16* ob = o + (size_t)b * HW_ * C_;
#pragma unroll
  for (int r = 0; r < 4; r++) {
    int m = m0 + w * 16 + quad * 4 + r;
    float inv = 1.0f / lb[m];
#pragma unroll
    for (int nt = 0; nt < 4; nt++) {
      int n = n0 + nt * 16 + col;
      ob[(size_t)m * C_ + n] = (bf16)(acc[0][nt][r] * inv);
    }
  }
}

// ---------------- Proj GEMM + residual: out = x + o*wp + bp (fp32) ----------
// 128x64 tile -> grid (64, 8) = 512 blocks (2/CU).
__global__ __launch_bounds__(256) void gemm_proj(const bf16* __restrict__ o,
                                                 const bf16* __restrict__ wtp,
                                                 const float* __restrict__ bp,
                                                 const float* __restrict__ x,
                                                 float* __restrict__ out) {
  int m0 = blockIdx.x * 128, n0 = blockIdx.y * 64;
  floatx4 acc[2][4];
  gemm_main<128, 64, 2, 4>(o + (size_t)m0 * C_, C_, wtp + (size_t)n0 * C_, C_, C_, acc);
  int tid = threadIdx.x, w = tid >> 6, lane = tid & 63;
  int col = lane & 15, quad = lane >> 4;
#pragma unroll
  for (int mt = 0; mt < 2; mt++)
#pragma unroll
    for (int nt = 0; nt < 4; nt++) {
      int n = n0 + nt * 16 + col;
      float bb = bp[n];
#pragma unroll
      for (int r = 0; r < 4; r++) {
        int m = m0 + w * 32 + mt * 16 + quad * 4 + r;
        out[(size_t)m * C_ + n] = x[(size_t)m * C_ + n] + acc[mt][nt][r] + bb;
      }
    }
}

// ---------------- launch -----------------------------------------------------
extern "C" void kernel_launch(void* const* d_in, const int* in_sizes, int n_in,
                              void* d_out, int out_size, void* d_ws, size_t ws_size,
                              hipStream_t stream) {
  const float* x     = (const float*)d_in[0];
  const float* gamma = (const float*)d_in[1];
  const float* beta  = (const float*)d_in[2];
  const float* wq    = (const float*)d_in[3];
  const float* bq    = (const float*)d_in[4];
  const float* wk    = (const float*)d_in[5];
  const float* bk    = (const float*)d_in[6];
  const float* wv    = (const float*)d_in[7];
  const float* bv    = (const float*)d_in[8];
  const float* wp    = (const float*)d_in[9];
  const float* bp    = (const float*)d_in[10];
  float* out = (float*)d_out;

  char* w8s = (char*)d_ws;
  float* stats = (float*)(w8s);                      // 512 B
  float* l     = (float*)(w8s + 65536u);             // 32 KB
  float* pp    = (float*)(w8s + 393216u);            // 128 KB
  uint8_t* w8  = (uint8_t*)(w8s + (1u << 20));       // 768 KB (fp8 wq/wk/wv ^T)
  bf16* wtp    = (bf16*)(w8s + (2u << 20));          // 512 KB (bf16 wp^T)
  uint8_t* h8  = (uint8_t*)(w8s + (4u << 20));       // 4 MB
  bf16* o      = (bf16*)(w8s + (8u << 20));          // 8 MB
  uint8_t* q8  = (uint8_t*)(w8s + (16u << 20));      // 4 MB
  uint8_t* k8  = (uint8_t*)(w8s + (20u << 20));      // 4 MB
  uint8_t* vt8 = (uint8_t*)(w8s + (24u << 20));      // 4 MB
  uint8_t* P8  = (uint8_t*)(w8s + (28u << 20));      // 32 MB -> 60 MB total

  hipMemsetAsync(l, 0, (size_t)M_ * sizeof(float), stream);
  gn_part<<<512, 256, 0, stream>>>(x, pp);
  gn_finish<<<64, 256, 0, stream>>>(pp, stats);
  gn_apply<<<4096, 256, 0, stream>>>(x, gamma, beta, stats, h8);
  wtrans<<<dim3(16, 16, 4), 256, 0, stream>>>(wq, wk, wv, wp, w8, wtp);
  gemm_qkv<<<dim3(M_ / 128, C_ / 64, 3), 256, 0, stream>>>(h8, w8, bq, bk, bv, q8, k8, vt8);
  gemm_qk<<<dim3(HW_ / 128, HW_ / 64, B_), 256, 0, stream>>>(q8, k8, P8, l);
  gemm_pv<<<dim3(HW_ / 64, C_ / 64, B_), 256, 0, stream>>>(P8, vt8, l, o);
  gemm_proj<<<dim3(M_ / 128, C_ / 64, 1), 256, 0, stream>>>(o, wtp, bp, x, out);
}

// Round 13
// 192.227 us; speedup vs baseline: 1.0852x; 1.0852x over previous
//
#include <hip/hip_runtime.h>
#include <hip/hip_bf16.h>
#include <cstdint>
#include <cstddef>

typedef __bf16 bf16;
typedef bf16 bf16x8 __attribute__((ext_vector_type(8)));
typedef bf16 bf16x4 __attribute__((ext_vector_type(4)));
typedef float floatx4 __attribute__((ext_vector_type(4)));
typedef int intx8 __attribute__((ext_vector_type(8)));

#define DEVI __device__ __forceinline__

#define C_  512
#define HW_ 4096
#define B_  2
#define M_  8192   // B_*HW_
#define TK  64

// Tile rule (R6/R12 evidence): keep >=8 MFMAs per barrier segment (128x64).
// 64x64 (4 MFMAs/iter) and 128x128-at-1-block/CU both regressed.

DEVI floatx4 mfma16(bf16x8 a, bf16x8 b, floatx4 c) {
  return __builtin_amdgcn_mfma_f32_16x16x32_bf16(a, b, c, 0, 0, 0);
}

// fp8 e4m3 MX-scaled MFMA with unit scales (E8M0 127 = 2^0): plain fp8 GEMM
// at 2x bf16 rate, K=128 per instruction.
DEVI floatx4 mfma_fp8(intx8 a, intx8 b, floatx4 c) {
  return __builtin_amdgcn_mfma_scale_f32_16x16x128_f8f6f4(a, b, c, 0, 0,
                                                          0, 127, 0, 127);
}

// Direct HBM->LDS DMA, 16B per lane. LDS dest is wave-uniform base + lane*16.
DEVI void gload16(const void* g, void* lds) {
  using gp = const __attribute__((address_space(1))) unsigned int*;
  using lp = __attribute__((address_space(3))) unsigned int*;
  __builtin_amdgcn_global_load_lds(
      reinterpret_cast<gp>(reinterpret_cast<uintptr_t>(g)),
      reinterpret_cast<lp>((unsigned int)(uintptr_t)lds), 16, 0, 0);
}

// float -> fp8 e4m3 byte (OCP on gfx950)
DEVI uint32_t f32_to_fp8(float x) {
  return (uint32_t)__builtin_amdgcn_cvt_pk_fp8_f32(x, x, 0, false) & 0xffu;
}
DEVI int pack4_fp8(float a, float b, float c, float d) {
  int pk = __builtin_amdgcn_cvt_pk_fp8_f32(a, b, 0, false);
  return __builtin_amdgcn_cvt_pk_fp8_f32(c, d, pk, true);
}

// ---- GroupNorm partial sums (512 blocks) + zero l (replaces memset) --------
__global__ __launch_bounds__(256) void gn_part(const float* __restrict__ x,
                                               float* __restrict__ pp,
                                               float* __restrict__ l) {
  int blk = blockIdx.x;              // 0..511
  int t = threadIdx.x;
  if (t < 16) l[blk * 16 + t] = 0.f; // 512*16 = 8192 = M_
  int batch = blk >> 8;
  int pix0 = (blk & 255) * 16;
  int c4 = (t & 127) << 2;           // channel quad (one group)
  int ph = t >> 7;                   // 0/1 pixel phase
  const float* px = x + (size_t)batch * HW_ * C_ + (size_t)(pix0 + ph) * C_ + c4;
  float s1 = 0.f, s2 = 0.f;
#pragma unroll
  for (int i = 0; i < 8; i++) {
    float4 v = *reinterpret_cast<const float4*>(px + (size_t)i * 2 * C_);
    s1 += v.x + v.y + v.z + v.w;
    s2 += v.x * v.x + v.y * v.y + v.z * v.z + v.w * v.w;
  }
  __shared__ float l1[256], l2[256];
  l1[t] = s1; l2[t] = s2;
  __syncthreads();
  if (t < 32) {                      // group g = t: slots g*4+j (+128)
    float a = 0.f, b2 = 0.f;
#pragma unroll
    for (int j = 0; j < 4; j++) {
      a  += l1[t * 4 + j] + l1[t * 4 + j + 128];
      b2 += l2[t * 4 + j] + l2[t * 4 + j + 128];
    }
    pp[blk * 32 + t] = a;
    pp[512 * 32 + blk * 32 + t] = b2;
  }
}

// ---- Fused: blocks 0..63 = gn_finish; blocks 64..1087 = weight transpose ---
// (independent work merged to cut a dispatch gap)
__global__ __launch_bounds__(256) void finish_wtrans(
    const float* __restrict__ pp, float* __restrict__ stats,
    const float* __restrict__ wq, const float* __restrict__ wk,
    const float* __restrict__ wv, const float* __restrict__ wp,
    uint8_t* __restrict__ w8, bf16* __restrict__ wtp) {
  int t = threadIdx.x;
  if (blockIdx.x < 64) {
    int bg = blockIdx.x;             // b*32+g
    int b = bg >> 5, g = bg & 31;
    float s1 = pp[(b * 256 + t) * 32 + g];
    float s2 = pp[512 * 32 + (b * 256 + t) * 32 + g];
    for (int off = 32; off; off >>= 1) {
      s1 += __shfl_down(s1, off);
      s2 += __shfl_down(s2, off);
    }
    __shared__ float r1[4], r2[4];
    int wid = t >> 6;
    if ((t & 63) == 0) { r1[wid] = s1; r2[wid] = s2; }
    __syncthreads();
    if (t == 0) {
      s1 = r1[0] + r1[1] + r1[2] + r1[3];
      s2 = r2[0] + r2[1] + r2[2] + r2[3];
      float inv = 1.0f / (HW_ * 16);
      float mean = s1 * inv;
      float var  = s2 * inv - mean * mean;
      stats[bg]      = mean;
      stats[64 + bg] = rsqrtf(var + 1e-5f);
    }
    return;
  }
  int id = blockIdx.x - 64;          // 0..1023: (z, 16x16 tile grid of 32x32)
  int z = id >> 8;
  int k0 = ((id >> 4) & 15) * 32, n0 = (id & 15) * 32;
  const float* w = (z == 0) ? wq : (z == 1) ? wk : (z == 2) ? wv : wp;
  __shared__ float tt[32][33];
  int r = t >> 5, cc = t & 31;
  for (int i = 0; i < 4; i++) {
    int rr = r + i * 8;
    tt[rr][cc] = w[(size_t)(k0 + rr) * C_ + n0 + cc];
  }
  __syncthreads();
  if (z < 3) {
    uint8_t* dst = w8 + (size_t)z * C_ * C_;
    for (int i = 0; i < 4; i++) {
      int rr = r + i * 8;
      dst[(size_t)(n0 + rr) * C_ + k0 + cc] = (uint8_t)f32_to_fp8(tt[cc][rr]);
    }
  } else {
    for (int i = 0; i < 4; i++) {
      int rr = r + i * 8;
      wtp[(size_t)(n0 + rr) * C_ + k0 + cc] = (bf16)tt[cc][rr];
    }
  }
}

// ---------------- Apply GN -> h8 fp8 (M_ x C_) ------------------------------
__global__ __launch_bounds__(256) void gn_apply(const float* __restrict__ x,
                                                const float* __restrict__ gamma,
                                                const float* __restrict__ beta,
                                                const float* __restrict__ stats,
                                                uint8_t* __restrict__ h8) {
  int idx = blockIdx.x * 256 + threadIdx.x;    // 4 elems each
  int m  = idx >> 7;
  int c4 = (idx & 127) << 2;
  int b = m >> 12;
  int g = c4 >> 4;
  float mean = stats[(b << 5) + g];
  float rs   = stats[64 + (b << 5) + g];
  const float4 xv = *reinterpret_cast<const float4*>(x + (size_t)m * C_ + c4);
  const float4 gv = *reinterpret_cast<const float4*>(gamma + c4);
  const float4 bv = *reinterpret_cast<const float4*>(beta + c4);
  int pk = pack4_fp8((xv.x - mean) * rs * gv.x + bv.x,
                     (xv.y - mean) * rs * gv.y + bv.y,
                     (xv.z - mean) * rs * gv.z + bv.z,
                     (xv.w - mean) * rs * gv.w + bv.w);
  *reinterpret_cast<int*>(h8 + (size_t)m * C_ + c4) = pk;
}

// ---- m97-style bf16 GEMM mainloop, templated tile: C(BM x BN) = A * Bt^T ---
// A-frag: A[m=lane&15][k=quad*8+j]; C/D: col=lane&15, row=quad*4+reg.
template <int BM, int BN, int MT, int NT>
DEVI void gemm_main(const bf16* __restrict__ A, int lda,
                    const bf16* __restrict__ Bt, int ldb,
                    int K, floatx4 (&acc)[MT][NT]) {
  constexpr int WCOLS = BN / (NT * 16);
  __shared__ __align__(16) bf16 As[BM * TK];
  __shared__ __align__(16) bf16 Bs[BN * TK];
  int tid = threadIdx.x;
  int w = tid >> 6, lane = tid & 63;
  int wrow = w / WCOLS, wcol = w % WCOLS;
  int col = lane & 15, quad = lane >> 4;
#pragma unroll
  for (int mt = 0; mt < MT; mt++)
#pragma unroll
    for (int nt = 0; nt < NT; nt++)
      acc[mt][nt] = floatx4{0.f, 0.f, 0.f, 0.f};
  for (int k0 = 0; k0 < K; k0 += TK) {
    __syncthreads();
#pragma unroll
    for (int i = 0; i < BM / 32; i++) {
      int id = tid + i * 256;                // row=id>>3, c8=id&7
      gload16(A + (size_t)(id >> 3) * lda + k0 + (id & 7) * 8, As + id * 8);
    }
#pragma unroll
    for (int i = 0; i < BN / 32; i++) {
      int id = tid + i * 256;
      gload16(Bt + (size_t)(id >> 3) * ldb + k0 + (id & 7) * 8, Bs + id * 8);
    }
    __syncthreads();                         // drains vmcnt -> LDS valid
#pragma unroll
    for (int kk = 0; kk < 2; kk++) {
      bf16x8 af[MT], bf[NT];
#pragma unroll
      for (int mt = 0; mt < MT; mt++)
        af[mt] = *reinterpret_cast<const bf16x8*>(
            As + (wrow * MT * 16 + mt * 16 + col) * TK + kk * 32 + quad * 8);
#pragma unroll
      for (int nt = 0; nt < NT; nt++)
        bf[nt] = *reinterpret_cast<const bf16x8*>(
            Bs + (wcol * NT * 16 + nt * 16 + col) * TK + kk * 32 + quad * 8);
#pragma unroll
      for (int mt = 0; mt < MT; mt++)
#pragma unroll
        for (int nt = 0; nt < NT; nt++)
          acc[mt][nt] = mfma16(af[mt], bf[nt], acc[mt][nt]);
    }
  }
}

// ---- fp8 MX GEMM mainloop: TK=128 bytes/row; A-frag 32B/lane (k=quad*32+j) -
template <int BM, int BN, int MT, int NT>
DEVI void gemm_fp8(const uint8_t* __restrict__ A, int lda,
                   const uint8_t* __restrict__ Bt, int ldb,
                   int K, floatx4 (&acc)[MT][NT]) {
  constexpr int WCOLS = BN / (NT * 16);
  __shared__ __align__(16) uint8_t As[BM * 128];
  __shared__ __align__(16) uint8_t Bs[BN * 128];
  int tid = threadIdx.x;
  int w = tid >> 6, lane = tid & 63;
  int wrow = w / WCOLS, wcol = w % WCOLS;
  int col = lane & 15, quad = lane >> 4;
#pragma unroll
  for (int mt = 0; mt < MT; mt++)
#pragma unroll
    for (int nt = 0; nt < NT; nt++)
      acc[mt][nt] = floatx4{0.f, 0.f, 0.f, 0.f};
  for (int k0 = 0; k0 < K; k0 += 128) {
    __syncthreads();
#pragma unroll
    for (int i = 0; i < BM / 32; i++) {      // row = id>>3 (8 lanes x 16B = 128B)
      int id = tid + i * 256;
      gload16(A + (size_t)(id >> 3) * lda + k0 + (id & 7) * 16, As + id * 16);
    }
#pragma unroll
    for (int i = 0; i < BN / 32; i++) {
      int id = tid + i * 256;
      gload16(Bt + (size_t)(id >> 3) * ldb + k0 + (id & 7) * 16, Bs + id * 16);
    }
    __syncthreads();                         // drains vmcnt -> LDS valid
    intx8 af[MT], bf[NT];
#pragma unroll
    for (int mt = 0; mt < MT; mt++)
      af[mt] = *reinterpret_cast<const intx8*>(
          As + (wrow * MT * 16 + mt * 16 + col) * 128 + quad * 32);
#pragma unroll
    for (int nt = 0; nt < NT; nt++)
      bf[nt] = *reinterpret_cast<const intx8*>(
          Bs + (wcol * NT * 16 + nt * 16 + col) * 128 + quad * 32);
#pragma unroll
    for (int mt = 0; mt < MT; mt++)
#pragma unroll
      for (int nt = 0; nt < NT; nt++)
        acc[mt][nt] = mfma_fp8(af[mt], bf[nt], acc[mt][nt]);
  }
}

// ---------------- QKV fp8 GEMM (h8 x w8): q8, k8, vt8 -----------------------
// 128x64 tile -> grid (64, 8, 3) = 1536 blocks (6/CU). K=512 -> 4 iters.
__global__ __launch_bounds__(256) void gemm_qkv(const uint8_t* __restrict__ h8,
                                                const uint8_t* __restrict__ w8,
                                                const float* __restrict__ bq,
                                                const float* __restrict__ bk,
                                                const float* __restrict__ bv,
                                                uint8_t* __restrict__ q8,
                                                uint8_t* __restrict__ k8,
                                                uint8_t* __restrict__ vt8) {
  int z = blockIdx.z;
  int m0 = blockIdx.x * 128, n0 = blockIdx.y * 64;
  floatx4 acc[2][4];
  gemm_fp8<128, 64, 2, 4>(h8 + (size_t)m0 * C_, C_,
                          w8 + (size_t)z * C_ * C_ + (size_t)n0 * C_, C_, C_, acc);
  int tid = threadIdx.x, w = tid >> 6, lane = tid & 63;
  int col = lane & 15, quad = lane >> 4;
  const float* bias = (z == 0) ? bq : (z == 1) ? bk : bv;
  if (z < 2) {
    uint8_t* out = (z == 0) ? q8 : k8;
#pragma unroll
    for (int mt = 0; mt < 2; mt++)
#pragma unroll
      for (int nt = 0; nt < 4; nt++) {
        int n = n0 + nt * 16 + col;
        float bb = bias[n];
#pragma unroll
        for (int r = 0; r < 4; r++) {
          int m = m0 + w * 32 + mt * 16 + quad * 4 + r;
          out[(size_t)m * C_ + n] = (uint8_t)f32_to_fp8(acc[mt][nt][r] + bb);
        }
      }
  } else {
    // vt8[b][c][s] = fp8(v[b*4096+s][c]); 4 consecutive s -> packed int store
#pragma unroll
    for (int mt = 0; mt < 2; mt++)
#pragma unroll
      for (int nt = 0; nt < 4; nt++) {
        int n = n0 + nt * 16 + col;
        float bb = bias[n];
        int mbase = m0 + w * 32 + mt * 16 + quad * 4;
        int b = mbase >> 12;
        int s = mbase & 4095;
        int pk = pack4_fp8(acc[mt][nt][0] + bb, acc[mt][nt][1] + bb,
                           acc[mt][nt][2] + bb, acc[mt][nt][3] + bb);
        *reinterpret_cast<int*>(vt8 + ((size_t)b * C_ + n) * HW_ + s) = pk;
      }
  }
}

// ---------------- QK^T fp8 GEMM -> P8 = fp8(exp(S*scale)), l += rowsum ------
// 128x64 tile -> grid (32, 64, B) = 4096 blocks (16/CU). K=512 -> 4 iters.
// l sums the PRE-ROUNDING float p (mean-zero fp8 rounding mismatch vs PV
// ~0.1% relative -> negligible).
__global__ __launch_bounds__(256) void gemm_qk(const uint8_t* __restrict__ q8,
                                               const uint8_t* __restrict__ k8,
                                               uint8_t* __restrict__ P8,
                                               float* __restrict__ l) {
  int b = blockIdx.z;
  int m0 = blockIdx.x * 128, n0 = blockIdx.y * 64;
  floatx4 acc[2][4];
  gemm_fp8<128, 64, 2, 4>(q8 + ((size_t)b * HW_ + m0) * C_, C_,
                          k8 + ((size_t)b * HW_ + n0) * C_, C_, C_, acc);
  int tid = threadIdx.x, w = tid >> 6, lane = tid & 63;
  int col = lane & 15, quad = lane >> 4;
  const float sl2e = 0.044194173824159216f * 1.4426950408889634f; // scale*log2e
  uint8_t* Pb = P8 + (size_t)b * HW_ * HW_;
  float* lb = l + (size_t)b * HW_;
#pragma unroll
  for (int mt = 0; mt < 2; mt++) {
    float rs[4] = {0.f, 0.f, 0.f, 0.f};
#pragma unroll
    for (int nt = 0; nt < 4; nt++) {
      int n = n0 + nt * 16 + col;
      float p0 = exp2f(acc[mt][nt][0] * sl2e);
      float p1 = exp2f(acc[mt][nt][1] * sl2e);
      float p2 = exp2f(acc[mt][nt][2] * sl2e);
      float p3 = exp2f(acc[mt][nt][3] * sl2e);
      int pk = pack4_fp8(p0, p1, p2, p3);
      size_t base = (size_t)(m0 + w * 32 + mt * 16 + quad * 4) * HW_ + n;
      Pb[base]           = (uint8_t)pk;
      Pb[base + HW_]     = (uint8_t)((unsigned)pk >> 8);
      Pb[base + 2 * HW_] = (uint8_t)((unsigned)pk >> 16);
      Pb[base + 3 * HW_] = (uint8_t)((unsigned)pk >> 24);
      rs[0] += p0; rs[1] += p1; rs[2] += p2; rs[3] += p3;
    }
    // reduce over the 16 col-lanes (xor keeps quad fixed)
#pragma unroll
    for (int off = 1; off < 16; off <<= 1)
#pragma unroll
      for (int r = 0; r < 4; r++)
        rs[r] += __shfl_xor(rs[r], off);
    if (col == 0)
#pragma unroll
      for (int r = 0; r < 4; r++)
        atomicAdd(&lb[m0 + w * 32 + mt * 16 + quad * 4 + r], rs[r]);
  }
}

// ---------------- PV fp8 GEMM: O = P8 * V8^T, normalize by l -> o bf16 ------
// 128x64 tile -> grid (32, 8, B) = 512 blocks (2/CU). K=4096 -> 32 iters.
__global__ __launch_bounds__(256) void gemm_pv(const uint8_t* __restrict__ P8,
                                               const uint8_t* __restrict__ vt8,
                                               const float* __restrict__ l,
                                               bf16* __restrict__ o) {
  int b = blockIdx.z;
  int m0 = blockIdx.x * 128, n0 = blockIdx.y * 64;
  floatx4 acc[2][4];
  gemm_fp8<128, 64, 2, 4>(P8 + (size_t)b * HW_ * HW_ + (size_t)m0 * HW_, HW_,
                          vt8 + ((size_t)b * C_ + n0) * HW_, HW_, HW_, acc);
  int tid = threadIdx.x, w = tid >> 6, lane = tid & 63;
  int col = lane & 15, quad = lane >> 4;
  const float* lb = l + (size_t)b * HW_;
  bf16* ob = o + (size_t)b * HW_ * C_;
#pragma unroll
  for (int mt = 0; mt < 2; mt++)
#pragma unroll
    for (int r = 0; r < 4; r++) {
      int m = m0 + w * 32 + mt * 16 + quad * 4 + r;
      float inv = 1.0f / lb[m];
#pragma unroll
      for (int nt = 0; nt < 4; nt++) {
        int n = n0 + nt * 16 + col;
        ob[(size_t)m * C_ + n] = (bf16)(acc[mt][nt][r] * inv);
      }
    }
}

// ---------------- Proj GEMM + residual: out = x + o*wp + bp (fp32) ----------
// 128x64 tile -> grid (64, 8) = 512 blocks (2/CU).
__global__ __launch_bounds__(256) void gemm_proj(const bf16* __restrict__ o,
                                                 const bf16* __restrict__ wtp,
                                                 const float* __restrict__ bp,
                                                 const float* __restrict__ x,
                                                 float* __restrict__ out) {
  int m0 = blockIdx.x * 128, n0 = blockIdx.y * 64;
  floatx4 acc[2][4];
  gemm_main<128, 64, 2, 4>(o + (size_t)m0 * C_, C_, wtp + (size_t)n0 * C_, C_, C_, acc);
  int tid = threadIdx.x, w = tid >> 6, lane = tid & 63;
  int col = lane & 15, quad = lane >> 4;
#pragma unroll
  for (int mt = 0; mt < 2; mt++)
#pragma unroll
    for (int nt = 0; nt < 4; nt++) {
      int n = n0 + nt * 16 + col;
      float bb = bp[n];
#pragma unroll
      for (int r = 0; r < 4; r++) {
        int m = m0 + w * 32 + mt * 16 + quad * 4 + r;
        out[(size_t)m * C_ + n] = x[(size_t)m * C_ + n] + acc[mt][nt][r] + bb;
      }
    }
}

// ---------------- launch -----------------------------------------------------
extern "C" void kernel_launch(void* const* d_in, const int* in_sizes, int n_in,
                              void* d_out, int out_size, void* d_ws, size_t ws_size,
                              hipStream_t stream) {
  const float* x     = (const float*)d_in[0];
  const float* gamma = (const float*)d_in[1];
  const float* beta  = (const float*)d_in[2];
  const float* wq    = (const float*)d_in[3];
  const float* bq    = (const float*)d_in[4];
  const float* wk    = (const float*)d_in[5];
  const float* bk    = (const float*)d_in[6];
  const float* wv    = (const float*)d_in[7];
  const float* bv    = (const float*)d_in[8];
  const float* wp    = (const float*)d_in[9];
  const float* bp    = (const float*)d_in[10];
  float* out = (float*)d_out;

  char* w8s = (char*)d_ws;
  float* stats = (float*)(w8s);                      // 512 B
  float* l     = (float*)(w8s + 65536u);             // 32 KB (zeroed by gn_part)
  float* pp    = (float*)(w8s + 393216u);            // 128 KB
  uint8_t* w8  = (uint8_t*)(w8s + (1u << 20));       // 768 KB (fp8 wq/wk/wv ^T)
  bf16* wtp    = (bf16*)(w8s + (2u << 20));          // 512 KB (bf16 wp^T)
  uint8_t* h8  = (uint8_t*)(w8s + (4u << 20));       // 4 MB
  bf16* o      = (bf16*)(w8s + (8u << 20));          // 8 MB
  uint8_t* q8  = (uint8_t*)(w8s + (16u << 20));      // 4 MB
  uint8_t* k8  = (uint8_t*)(w8s + (20u << 20));      // 4 MB
  uint8_t* vt8 = (uint8_t*)(w8s + (24u << 20));      // 4 MB
  uint8_t* P8  = (uint8_t*)(w8s + (28u << 20));      // 32 MB -> 60 MB total

  gn_part<<<512, 256, 0, stream>>>(x, pp, l);
  finish_wtrans<<<1088, 256, 0, stream>>>(pp, stats, wq, wk, wv, wp, w8, wtp);
  gn_apply<<<4096, 256, 0, stream>>>(x, gamma, beta, stats, h8);
  gemm_qkv<<<dim3(M_ / 128, C_ / 64, 3), 256, 0, stream>>>(h8, w8, bq, bk, bv, q8, k8, vt8);
  gemm_qk<<<dim3(HW_ / 128, HW_ / 64, B_), 256, 0, stream>>>(q8, k8, P8, l);
  gemm_pv<<<dim3(HW_ / 128, C_ / 64, B_), 256, 0, stream>>>(P8, vt8, l, o);
  gemm_proj<<<dim3(M_ / 128, C_ / 64, 1), 256, 0, stream>>>(o, wtp, bp, x, out);
}